// Round 2
// baseline (93.264 us; speedup 1.0000x reference)
//
#include <hip/hip_runtime.h>

// CostVolume: out (1, 2C, D4, H, W) fp32
//   c <  C : left [c,h,w]     if w >= d else 0
//   c >= C : right[c-C,h,w-d] if w >= d else 0
// Shapes fixed by the problem: C=32, H=128, W=240, D4=192/4=48.

constexpr int C  = 32;
constexpr int H  = 128;
constexpr int W  = 240;
constexpr int D4 = 48;
constexpr int W4 = W / 4;                         // 60 float4 per row
constexpr int TOTAL4 = 2 * C * D4 * H * W4;       // 23,592,960 float4 stores

typedef float f32x4 __attribute__((ext_vector_type(4)));  // native vector for
                                                          // nontemporal builtin

__global__ void __launch_bounds__(256) cost_volume_kernel(
    const float* __restrict__ left,
    const float* __restrict__ right,
    float* __restrict__ out) {
    const int stride = gridDim.x * blockDim.x;
    for (int idx = blockIdx.x * blockDim.x + threadIdx.x; idx < TOTAL4;
         idx += stride) {
        // Decompose: idx = ((c*D4 + d)*H + h)*W4 + w4   (compile-time consts
        // -> compiler emits magic-multiply div/mod, no real divides)
        int w4 = idx % W4;
        int t  = idx / W4;
        int h  = t % H;
        t /= H;
        int d = t % D4;
        int c = t / D4;

        const int w0 = w4 * 4;
        const bool is_left = (c < C);
        // Row base of the source feature map for this (c,h)
        const float* __restrict__ src =
            is_left ? (left + (c * H + h) * W)
                    : (right + ((c - C) * H + h) * W);
        const int shift = is_left ? 0 : d;  // right volume reads w-d

        f32x4 vec;
#pragma unroll
        for (int j = 0; j < 4; ++j) {
            const int wj = w0 + j;
            // mask: w >= d. When true and c>=C, wj-d is in [0, W-1] so the
            // reference's clip() is a no-op; value-select keeps the masked
            // lane from mattering (wj-shift is still a valid address for
            // is_left, and for right we only use the load when wj>=d).
            vec[j] = (wj >= d) ? src[wj - shift] : 0.0f;
        }

        // Output is written once and never re-read by us: nontemporal store.
        __builtin_nontemporal_store(vec, reinterpret_cast<f32x4*>(out) + idx);
    }
}

extern "C" void kernel_launch(void* const* d_in, const int* in_sizes, int n_in,
                              void* d_out, int out_size, void* d_ws,
                              size_t ws_size, hipStream_t stream) {
    const float* left  = (const float*)d_in[0];
    const float* right = (const float*)d_in[1];
    // d_in[2] = max_disparity (scalar, fixed at 192 -> D4=48, baked in)
    float* out = (float*)d_out;

    // Memory-bound: cap grid at ~2048 blocks (8 blocks/CU across 256 CUs),
    // grid-stride the rest (~45 float4 stores per thread).
    const int block = 256;
    const int grid  = 2048;
    cost_volume_kernel<<<grid, block, 0, stream>>>(left, right, out);
}

// Round 3
// 77.432 us; speedup vs baseline: 1.2045x; 1.2045x over previous
//
#include <hip/hip_runtime.h>

// CostVolume: out (1, 2C, D4, H, W) fp32
//   c <  C : left [c,h,w]     if w >= d else 0
//   c >= C : right[c-C,h,w-d] if w >= d else 0
// C=32, H=128, W=240, D4=48. Output 377.5 MB -> pure write-BW problem.
//
// One block per (c2,h) source row: stage the 960 B row in LDS once, then
// write all 48 d-slices from it. Reads: 7.9 MB HBM total (once). Stores:
// each wave owns one d-slice per pass (d uniform per wave).

constexpr int C  = 32;
constexpr int H  = 128;
constexpr int W  = 240;
constexpr int D4 = 48;
constexpr int W4 = W / 4;              // 60 float4 per row

typedef float f32x4 __attribute__((ext_vector_type(4)));

// LDS pad: +1 float per 32 so lane-stride-4-float scalar reads hit
// 32 distinct banks (2 lanes/bank = free) instead of 8 lanes/bank.
__device__ __forceinline__ int pidx(int w) { return w + (w >> 5); }

__global__ void __launch_bounds__(256) cost_volume_kernel(
    const float* __restrict__ left,
    const float* __restrict__ right,
    float* __restrict__ out) {
    __shared__ float row[W + (W >> 5)];   // 247 floats, padded

    const int blk = blockIdx.x;           // 0 .. 64*128-1
    const int h   = blk & (H - 1);
    const int c2  = blk >> 7;             // 0..63
    const bool is_left = (c2 < C);
    const float* __restrict__ src =
        is_left ? (left  + (c2 * H + h) * W)
                : (right + ((c2 - C) * H + h) * W);

    const int tid = threadIdx.x;
    if (tid < W) row[pidx(tid)] = src[tid];   // coalesced 240-dword stage
    __syncthreads();

    const int lane = tid & 63;
    const int wave = tid >> 6;            // 4 waves: d = pass*4 + wave
    if (lane >= W4) return;               // 60 of 64 lanes store

    const int w0 = lane * 4;
    f32x4* __restrict__ out4 = reinterpret_cast<f32x4*>(out);
    const int base    = (c2 * D4 * H + h) * W4 + lane;  // d=0 slice
    const int dstride = H * W4;                          // 7680 float4 per d

#pragma unroll
    for (int pass = 0; pass < D4 / 4; ++pass) {
        const int d     = pass * 4 + wave;     // uniform per wave
        const int shift = is_left ? 0 : d;
        f32x4 v;
#pragma unroll
        for (int j = 0; j < 4; ++j) {
            const int wj = w0 + j;
            // w >= d guarantees wj - d in [0, W-1]; LDS read is in-bounds
            // either way since wj - shift <= wj < W and >= 0 when selected.
            v[j] = (wj >= d) ? row[pidx(wj - shift)] : 0.0f;
        }
        __builtin_nontemporal_store(v, out4 + base + d * dstride);
    }
}

extern "C" void kernel_launch(void* const* d_in, const int* in_sizes, int n_in,
                              void* d_out, int out_size, void* d_ws,
                              size_t ws_size, hipStream_t stream) {
    const float* left  = (const float*)d_in[0];
    const float* right = (const float*)d_in[1];
    float* out = (float*)d_out;

    const int grid  = 2 * C * H;   // 8192 blocks, one per (c2,h) row
    const int block = 256;
    cost_volume_kernel<<<grid, block, 0, stream>>>(left, right, out);
}